// Round 1
// baseline (444.001 us; speedup 1.0000x reference)
//
#include <hip/hip_runtime.h>

// Problem constants: E=800000 (=3125*256), N=50000, G=16, EMB=64.
#define EMB  64
#define NREP 256   // replica lines for per-graph global atomic spreading

typedef __attribute__((ext_vector_type(8))) short bf16x8;
typedef __attribute__((ext_vector_type(4))) float f32x4;
union BF8 { bf16x8 v; short s[8]; unsigned u[4]; };

// float -> bf16 bits, round-to-nearest-even (finite inputs).
static __device__ __forceinline__ short f2bf(float f) {
    unsigned u = __float_as_uint(f);
    u += 0x7fffu + ((u >> 16) & 1u);
    return (short)(u >> 16);
}

// 2x float -> packed bf16 pair in one instruction (RNE, bit-identical to f2bf).
static __device__ __forceinline__ unsigned cvt2(float lo, float hi) {
    unsigned r;
    asm("v_cvt_pk_bf16_f32 %0, %1, %2" : "=v"(r) : "v"(lo), "v"(hi));
    return r;
}

// ---------------------------------------------------------------------------
// Prep: ecnt histogram (scattered int atomics over 50k lines) + sorted-batch
// segment starts. Unchanged this round; if it surfaces in top-5 next round
// it becomes the target.
// ---------------------------------------------------------------------------
__global__ __launch_bounds__(256) void prep_kernel(
    const int* __restrict__ eidx, int* __restrict__ ecnt, int E,
    const int* __restrict__ batch, int* __restrict__ gStart, int N)
{
    int t = blockIdx.x * 256 + threadIdx.x;
    if (t < N) {
        int g = batch[t];
        if (t == 0 || batch[t - 1] != g) gStart[g] = t;
    }
    if (t < E) atomicAdd(&ecnt[eidx[t]], 1);
}

// ---------------------------------------------------------------------------
// Edge kernel v2: same transposed-MFMA math as v1, plus
//  * 2-stage ping-pong software pipeline over the 4 nt sub-tiles (the old
//    `#pragma unroll 1` was a scheduling fence: each nt stalled ~600-900cy on
//    its x/dvec/eidx loads; now stage nt+1 issues before nt's silu block)
//  * v_cvt_pk_bf16_f32 for the B fragments (8 insts vs ~56 VALU ops)
//  * silu algebra: arg = fma(a*NL2E, y, b*NL2E), w2*z = fma(a, w2*y, w2*b)
//    with b*NL2E and w2*b precomputed in LDS -> 4.2 VALU/eval (was 5) and two
//    short independent chains feeding the final fma
//  * invalid-edge handling folded into scale=0 (branchless scatter)
// ---------------------------------------------------------------------------
__global__ __launch_bounds__(256, 4) void edge_kernel(
    const float* __restrict__ dvec, const float* __restrict__ x_edge,
    const int*   __restrict__ eidx, const int* __restrict__ batch,
    const int*   __restrict__ ecnt,
    const float* __restrict__ W1, const float* __restrict__ b1,
    const float* __restrict__ W2, const float* __restrict__ b2,
    float* __restrict__ repsum, int E)
{
    __shared__ float bins[96];
    __shared__ float sb1N[64], sw2[64], sw2b[64];
    const int tid = threadIdx.x;
    const float NL2E = -1.442695040888963f;  // -log2(e)
    if (tid < 96) bins[tid] = 0.f;
    if (tid < 64) {
        float b = b1[tid], w = W2[tid];
        sb1N[tid] = b * NL2E;   // pre-folded exp2 bias
        sw2[tid]  = w;
        sw2b[tid] = w * b;      // pre-folded w2*z bias
    }
    __syncthreads();

    const int lane = tid & 63, wave = tid >> 6;
    const int col  = lane & 15, quad = lane >> 4;

    // A fragments: A[m=mt*16+col][k=kt*32+quad*8+j] = W1[k][m]  (bf16 RNE)
    BF8 Af[4][2];
    #pragma unroll
    for (int mt = 0; mt < 4; ++mt)
        #pragma unroll
        for (int kt = 0; kt < 2; ++kt) {
            const float* wp = W1 + (kt * 32 + quad * 8) * 64 + mt * 16 + col;
            #pragma unroll
            for (int j = 0; j < 8; ++j) Af[mt][kt].s[j] = f2bf(wp[j * 64]);
        }

    const float bb2  = b2[0];
    const long  ebase = (long)blockIdx.x * 256 + wave * 64;

// Issue all global loads for sub-tile NT into one stage register set.
#define PIPE_ISSUE(NT, XA, XB, XC, XD, DD0, DD1, DD2, NN, VM)                  \
    {                                                                          \
        long e_ = ebase + (NT) * 16 + col;                                     \
        VM = (e_ < E);                                                         \
        if (!VM) e_ = 0;                                                       \
        const float* xp_ = x_edge + (size_t)e_ * EMB + quad * 8;               \
        XA = *(const f32x4*)(xp_);                                             \
        XB = *(const f32x4*)(xp_ + 4);                                         \
        XC = *(const f32x4*)(xp_ + 32);                                        \
        XD = *(const f32x4*)(xp_ + 36);                                        \
        DD0 = dvec[3 * e_ + 0];                                                \
        DD1 = dvec[3 * e_ + 1];                                                \
        DD2 = dvec[3 * e_ + 2];                                                \
        if (quad < 2) NN = eidx[e_];                                           \
    }

// Consume one stage; PRE (the next stage's PIPE_ISSUE) is placed after the
// B-conversion and before the MFMA+silu block so its latency hides there.
#define PIPE_BODY(XA, XB, XC, XD, DD0, DD1, DD2, NN, VM, PRE)                  \
    {                                                                          \
        float scale_ = 0.f; int g_ = 0;                                        \
        if (quad < 2) {                                                        \
            int cnt_ = max(ecnt[NN], 1);                                       \
            g_ = batch[NN];                                                    \
            scale_ = __builtin_amdgcn_rcpf((float)cnt_);                       \
            if (!VM) scale_ = 0.f;                                             \
        }                                                                      \
        BF8 B0_, B1_;                                                          \
        B0_.u[0] = cvt2(XA.x, XA.y); B0_.u[1] = cvt2(XA.z, XA.w);              \
        B0_.u[2] = cvt2(XB.x, XB.y); B0_.u[3] = cvt2(XB.z, XB.w);              \
        B1_.u[0] = cvt2(XC.x, XC.y); B1_.u[1] = cvt2(XC.z, XC.w);              \
        B1_.u[2] = cvt2(XD.x, XD.y); B1_.u[3] = cvt2(XD.z, XD.w);              \
        float a_[6] = { DD0*DD0, DD1*DD1, DD2*DD2, DD0*DD1, DD0*DD2, DD1*DD2 };\
        float aN_[6];                                                          \
        _Pragma("unroll")                                                      \
        for (int c = 0; c < 6; ++c) aN_[c] = a_[c] * NL2E;                     \
        PRE                                                                    \
        float acc_[6] = { 0.f, 0.f, 0.f, 0.f, 0.f, 0.f };                      \
        _Pragma("unroll")                                                      \
        for (int mt = 0; mt < 4; ++mt) {                                       \
            f32x4 D_ = { 0.f, 0.f, 0.f, 0.f };                                 \
            D_ = __builtin_amdgcn_mfma_f32_16x16x32_bf16(Af[mt][0].v, B0_.v, D_, 0, 0, 0); \
            D_ = __builtin_amdgcn_mfma_f32_16x16x32_bf16(Af[mt][1].v, B1_.v, D_, 0, 0, 0); \
            _Pragma("unroll")                                                  \
            for (int r = 0; r < 4; ++r) {                                      \
                int   o_  = mt * 16 + quad * 4 + r;                            \
                float y_  = D_[r];                                             \
                float bN_ = sb1N[o_];                                          \
                float wy_ = sw2[o_] * y_;                                      \
                float wb_ = sw2b[o_];                                          \
                _Pragma("unroll")                                              \
                for (int c = 0; c < 6; ++c) {                                  \
                    float arg_ = fmaf(aN_[c], y_, bN_);                        \
                    float ex_  = __builtin_amdgcn_exp2f(arg_);                 \
                    float rr_  = __builtin_amdgcn_rcpf(1.0f + ex_);            \
                    float w2z_ = fmaf(a_[c], wy_, wb_);                        \
                    acc_[c]    = fmaf(w2z_, rr_, acc_[c]);                     \
                }                                                              \
            }                                                                  \
        }                                                                      \
        _Pragma("unroll")                                                      \
        for (int c = 0; c < 6; ++c) {                                          \
            acc_[c] += __shfl_xor(acc_[c], 16, 64);                            \
            acc_[c] += __shfl_xor(acc_[c], 32, 64);                            \
        }                                                                      \
        if (quad < 2) {                                                        \
            _Pragma("unroll")                                                  \
            for (int j = 0; j < 3; ++j) {                                      \
                int c = quad * 3 + j;                                          \
                atomicAdd(&bins[g_ * 6 + c], (acc_[c] + bb2) * scale_);        \
            }                                                                  \
        }                                                                      \
    }

    f32x4 Pxa, Pxb, Pxc, Pxd; float Pd0, Pd1, Pd2; int Pn = 0; bool Pv;
    f32x4 Qxa, Qxb, Qxc, Qxd; float Qd0, Qd1, Qd2; int Qn = 0; bool Qv;

    PIPE_ISSUE(0, Pxa, Pxb, Pxc, Pxd, Pd0, Pd1, Pd2, Pn, Pv)
    PIPE_BODY(Pxa, Pxb, Pxc, Pxd, Pd0, Pd1, Pd2, Pn, Pv,
              PIPE_ISSUE(1, Qxa, Qxb, Qxc, Qxd, Qd0, Qd1, Qd2, Qn, Qv))
    PIPE_BODY(Qxa, Qxb, Qxc, Qxd, Qd0, Qd1, Qd2, Qn, Qv,
              PIPE_ISSUE(2, Pxa, Pxb, Pxc, Pxd, Pd0, Pd1, Pd2, Pn, Pv))
    PIPE_BODY(Pxa, Pxb, Pxc, Pxd, Pd0, Pd1, Pd2, Pn, Pv,
              PIPE_ISSUE(3, Qxa, Qxb, Qxc, Qxd, Qd0, Qd1, Qd2, Qn, Qv))
    PIPE_BODY(Qxa, Qxb, Qxc, Qxd, Qd0, Qd1, Qd2, Qn, Qv, )

#undef PIPE_ISSUE
#undef PIPE_BODY

    __syncthreads();
    if (tid < 96) {
        int rep = blockIdx.x & (NREP - 1);
        atomicAdd(repsum + (size_t)rep * 96 + tid, bins[tid]);
    }
}

// ---------------------------------------------------------------------------
// Final: sum replicas (4-way parallel over reps), node counts from sorted
// boundaries, divide, expand 6 symmetric comps -> 9.
// ---------------------------------------------------------------------------
__global__ __launch_bounds__(384) void final_kernel(
    const float* __restrict__ repsum, const int* __restrict__ gStart,
    float* __restrict__ out, int N)
{
    __shared__ float part[4][96];
    __shared__ float sh[96];
    __shared__ int gs[17];
    int t = threadIdx.x;            // 384 threads
    int r0 = t / 96, gc = t % 96;   // r0 in 0..3
    float s = 0.f;
    #pragma unroll 8
    for (int r = r0; r < NREP; r += 4) s += repsum[(size_t)r * 96 + gc];
    part[r0][gc] = s;
    if (t == 0) {
        gs[16] = N;
        for (int g = 15; g >= 0; --g) {
            unsigned v = (unsigned)gStart[g];
            gs[g] = (v > (unsigned)gs[g + 1]) ? gs[g + 1] : (int)v;  // empty graphs
        }
    }
    __syncthreads();
    if (t < 96) sh[t] = part[0][t] + part[1][t] + part[2][t] + part[3][t];
    __syncthreads();
    if (t < 16) {
        int gN = gs[t + 1] - gs[t];
        float inv = 1.0f / fmaxf((float)gN, 1.0f);
        float m0 = sh[t * 6 + 0] * inv;
        float m1 = sh[t * 6 + 1] * inv;
        float m2 = sh[t * 6 + 2] * inv;
        float m3 = sh[t * 6 + 3] * inv;
        float m4 = sh[t * 6 + 4] * inv;
        float m5 = sh[t * 6 + 5] * inv;
        float* p = out + t * 9;
        p[0] = m0; p[1] = m3; p[2] = m4;
        p[3] = m3; p[4] = m1; p[5] = m5;
        p[6] = m4; p[7] = m5; p[8] = m2;
    }
}

// ---------------------------------------------------------------------------
extern "C" void kernel_launch(void* const* d_in, const int* in_sizes, int n_in,
                              void* d_out, int out_size, void* d_ws, size_t ws_size,
                              hipStream_t stream) {
    const float* dvec   = (const float*)d_in[0];   // [E,3]
    const float* x_edge = (const float*)d_in[1];   // [E,64]
    const int*   eidx   = (const int*)d_in[2];     // [E]
    const int*   batch  = (const int*)d_in[3];     // [N] sorted
    const float* W1     = (const float*)d_in[6];   // [64,64] (in,out)
    const float* b1     = (const float*)d_in[7];   // [64]
    const float* W2     = (const float*)d_in[8];   // [64,1]
    const float* b2     = (const float*)d_in[9];   // [1]

    int E = in_sizes[0] / 3;   // 800000
    int N = in_sizes[3];       // 50000

    // ws: ecnt[N] int | repsum[NREP*96] float | gStart[17] int  (contiguous)
    int*   ecnt   = (int*)d_ws;
    float* repsum = (float*)(ecnt + N);
    int*   gStart = (int*)(repsum + (size_t)NREP * 96);

    hipMemsetAsync(d_ws, 0, ((size_t)N + (size_t)NREP * 96) * 4, stream);
    hipMemsetAsync(gStart, 0xFF, 17 * 4, stream);

    int blocks = (E + 255) / 256;   // covers both E and N in prep
    prep_kernel<<<blocks, 256, 0, stream>>>(eidx, ecnt, E, batch, gStart, N);
    edge_kernel<<<blocks, 256, 0, stream>>>(dvec, x_edge, eidx, batch, ecnt,
                                            W1, b1, W2, b2, repsum, E);
    final_kernel<<<1, 384, 0, stream>>>(repsum, gStart, (float*)d_out, N);
}

// Round 2
// 367.649 us; speedup vs baseline: 1.2077x; 1.2077x over previous
//
#include <hip/hip_runtime.h>

// Problem constants: E=800000 (=3125*256), N=50000, G=16, EMB=64.
#define EMB  64
#define NREP 256   // replica lines for per-graph global atomic spreading

typedef __attribute__((ext_vector_type(8))) short bf16x8;
typedef __attribute__((ext_vector_type(4))) float f32x4;
union BF8 { bf16x8 v; short s[8]; unsigned u[4]; };

// float -> bf16 bits, round-to-nearest-even (finite inputs).
static __device__ __forceinline__ short f2bf(float f) {
    unsigned u = __float_as_uint(f);
    u += 0x7fffu + ((u >> 16) & 1u);
    return (short)(u >> 16);
}

// 2x float -> packed bf16 pair in one instruction (RNE, bit-identical to f2bf).
static __device__ __forceinline__ unsigned cvt2(float lo, float hi) {
    unsigned r;
    asm("v_cvt_pk_bf16_f32 %0, %1, %2" : "=v"(r) : "v"(lo), "v"(hi));
    return r;
}

// ---------------------------------------------------------------------------
// Prep: ecnt histogram (scattered int atomics over 50k lines) + sorted-batch
// segment starts.
// ---------------------------------------------------------------------------
__global__ __launch_bounds__(256) void prep_kernel(
    const int* __restrict__ eidx, int* __restrict__ ecnt, int E,
    const int* __restrict__ batch, int* __restrict__ gStart, int N)
{
    int t = blockIdx.x * 256 + threadIdx.x;
    if (t < N) {
        int g = batch[t];
        if (t == 0 || batch[t - 1] != g) gStart[g] = t;
    }
    if (t < E) atomicAdd(&ecnt[eidx[t]], 1);
}

// ---------------------------------------------------------------------------
// Edge kernel v3. R1 post-mortem: v2's 2-stage pipeline spilled (~260 B/thr
// scratch -> WRITE_SIZE 211MB) under __launch_bounds__(256,4)'s 128-reg
// unified VGPR+AGPR cap; v1 already spilled ~75 B/thr (its 60MB WRITE).
// Fixes here:
//  * __launch_bounds__(256,3): ~168-reg budget. v1 ran 3 waves/SIMD anyway
//    (38% occupancy), so no occupancy loss -- just no spills.
//  * Scatter metadata chain (eidx->ecnt,batch: two DEPENDENT global loads)
//    hoisted to the prologue for all 4 sub-tiles, overlapping the Af build.
//    In-loop pipeline stage is only x(16)+dvec(3) = 19 regs.
//  * Keep: 2-stage ping-pong over x/dvec, v_cvt_pk_bf16_f32 B-conversion,
//    silu algebra with pre-folded b1*(-log2e) and W2*b1 in LDS.
// ---------------------------------------------------------------------------
__global__ __launch_bounds__(256, 3) void edge_kernel(
    const float* __restrict__ dvec, const float* __restrict__ x_edge,
    const int*   __restrict__ eidx, const int* __restrict__ batch,
    const int*   __restrict__ ecnt,
    const float* __restrict__ W1, const float* __restrict__ b1,
    const float* __restrict__ W2, const float* __restrict__ b2,
    float* __restrict__ repsum, int E)
{
    __shared__ float bins[96];
    __shared__ float sb1N[64], sw2[64], sw2b[64];
    const int tid = threadIdx.x;
    const float NL2E = -1.442695040888963f;  // -log2(e)
    if (tid < 96) bins[tid] = 0.f;
    if (tid < 64) {
        float b = b1[tid], w = W2[tid];
        sb1N[tid] = b * NL2E;   // pre-folded exp2 bias
        sw2[tid]  = w;
        sw2b[tid] = w * b;      // pre-folded w2*z bias
    }
    __syncthreads();

    const int lane = tid & 63, wave = tid >> 6;
    const int col  = lane & 15, quad = lane >> 4;
    const long ebase = (long)blockIdx.x * 256 + wave * 64;

    // --- Prologue part 1: issue the scatter-metadata chain early (it is two
    // dependent global loads; its latency hides under the Af build below).
    int nn[4] = {0, 0, 0, 0};
    if (quad < 2) {
        #pragma unroll
        for (int nt = 0; nt < 4; ++nt) {
            long e = ebase + nt * 16 + col;
            if (e >= E) e = 0;
            nn[nt] = eidx[e];
        }
    }

    // --- Prologue part 2: A fragments (W1 is 16KB, L2-hot).
    // A[m=mt*16+col][k=kt*32+quad*8+j] = W1[k][m]  (bf16 RNE)
    BF8 Af[4][2];
    #pragma unroll
    for (int mt = 0; mt < 4; ++mt)
        #pragma unroll
        for (int kt = 0; kt < 2; ++kt) {
            const float* wp = W1 + (kt * 32 + quad * 8) * 64 + mt * 16 + col;
            #pragma unroll
            for (int j = 0; j < 8; ++j) Af[mt][kt].s[j] = f2bf(wp[j * 64]);
        }

    // --- Prologue part 3: resolve metadata (ecnt/batch loads depend on nn).
    float scl[4] = {0.f, 0.f, 0.f, 0.f};
    int   gg[4]  = {0, 0, 0, 0};
    if (quad < 2) {
        #pragma unroll
        for (int nt = 0; nt < 4; ++nt) {
            long e = ebase + nt * 16 + col;
            float s = __builtin_amdgcn_rcpf((float)max(ecnt[nn[nt]], 1));
            scl[nt] = (e < E) ? s : 0.f;
            gg[nt]  = batch[nn[nt]];
        }
    }

    const float bb2 = b2[0];

// Issue x/dvec loads for sub-tile NT into one stage register set (19 regs).
#define PIPE_ISSUE(NT, XA, XB, XC, XD, DD0, DD1, DD2)                          \
    {                                                                          \
        long e_ = ebase + (NT) * 16 + col;                                     \
        if (e_ >= E) e_ = 0;                                                   \
        const float* xp_ = x_edge + (size_t)e_ * EMB + quad * 8;               \
        XA = *(const f32x4*)(xp_);                                             \
        XB = *(const f32x4*)(xp_ + 4);                                         \
        XC = *(const f32x4*)(xp_ + 32);                                        \
        XD = *(const f32x4*)(xp_ + 36);                                        \
        DD0 = dvec[3 * e_ + 0];                                                \
        DD1 = dvec[3 * e_ + 1];                                                \
        DD2 = dvec[3 * e_ + 2];                                                \
    }

// Consume one stage; PRE (the next stage's PIPE_ISSUE) is placed after the
// B-conversion so its latency hides under the MFMA+silu block.
#define PIPE_BODY(NT, XA, XB, XC, XD, DD0, DD1, DD2, PRE)                      \
    {                                                                          \
        BF8 B0_, B1_;                                                          \
        B0_.u[0] = cvt2(XA.x, XA.y); B0_.u[1] = cvt2(XA.z, XA.w);              \
        B0_.u[2] = cvt2(XB.x, XB.y); B0_.u[3] = cvt2(XB.z, XB.w);              \
        B1_.u[0] = cvt2(XC.x, XC.y); B1_.u[1] = cvt2(XC.z, XC.w);              \
        B1_.u[2] = cvt2(XD.x, XD.y); B1_.u[3] = cvt2(XD.z, XD.w);              \
        float a_[6] = { DD0*DD0, DD1*DD1, DD2*DD2, DD0*DD1, DD0*DD2, DD1*DD2 };\
        float aN_[6];                                                          \
        _Pragma("unroll")                                                      \
        for (int c = 0; c < 6; ++c) aN_[c] = a_[c] * NL2E;                     \
        PRE                                                                    \
        float acc_[6] = { 0.f, 0.f, 0.f, 0.f, 0.f, 0.f };                      \
        _Pragma("unroll")                                                      \
        for (int mt = 0; mt < 4; ++mt) {                                       \
            f32x4 D_ = { 0.f, 0.f, 0.f, 0.f };                                 \
            D_ = __builtin_amdgcn_mfma_f32_16x16x32_bf16(Af[mt][0].v, B0_.v, D_, 0, 0, 0); \
            D_ = __builtin_amdgcn_mfma_f32_16x16x32_bf16(Af[mt][1].v, B1_.v, D_, 0, 0, 0); \
            _Pragma("unroll")                                                  \
            for (int r = 0; r < 4; ++r) {                                      \
                int   o_  = mt * 16 + quad * 4 + r;                            \
                float y_  = D_[r];                                             \
                float bN_ = sb1N[o_];                                          \
                float wy_ = sw2[o_] * y_;                                      \
                float wb_ = sw2b[o_];                                          \
                _Pragma("unroll")                                              \
                for (int c = 0; c < 6; ++c) {                                  \
                    float arg_ = fmaf(aN_[c], y_, bN_);                        \
                    float ex_  = __builtin_amdgcn_exp2f(arg_);                 \
                    float rr_  = __builtin_amdgcn_rcpf(1.0f + ex_);            \
                    float w2z_ = fmaf(a_[c], wy_, wb_);                        \
                    acc_[c]    = fmaf(w2z_, rr_, acc_[c]);                     \
                }                                                              \
            }                                                                  \
        }                                                                      \
        _Pragma("unroll")                                                      \
        for (int c = 0; c < 6; ++c) {                                          \
            acc_[c] += __shfl_xor(acc_[c], 16, 64);                            \
            acc_[c] += __shfl_xor(acc_[c], 32, 64);                            \
        }                                                                      \
        if (quad < 2) {                                                        \
            _Pragma("unroll")                                                  \
            for (int j = 0; j < 3; ++j) {                                      \
                int c = quad * 3 + j;                                          \
                atomicAdd(&bins[gg[NT] * 6 + c], (acc_[c] + bb2) * scl[NT]);   \
            }                                                                  \
        }                                                                      \
    }

    f32x4 Pxa, Pxb, Pxc, Pxd; float Pd0, Pd1, Pd2;
    f32x4 Qxa, Qxb, Qxc, Qxd; float Qd0, Qd1, Qd2;

    PIPE_ISSUE(0, Pxa, Pxb, Pxc, Pxd, Pd0, Pd1, Pd2)
    PIPE_BODY(0, Pxa, Pxb, Pxc, Pxd, Pd0, Pd1, Pd2,
              PIPE_ISSUE(1, Qxa, Qxb, Qxc, Qxd, Qd0, Qd1, Qd2))
    PIPE_BODY(1, Qxa, Qxb, Qxc, Qxd, Qd0, Qd1, Qd2,
              PIPE_ISSUE(2, Pxa, Pxb, Pxc, Pxd, Pd0, Pd1, Pd2))
    PIPE_BODY(2, Pxa, Pxb, Pxc, Pxd, Pd0, Pd1, Pd2,
              PIPE_ISSUE(3, Qxa, Qxb, Qxc, Qxd, Qd0, Qd1, Qd2))
    PIPE_BODY(3, Qxa, Qxb, Qxc, Qxd, Qd0, Qd1, Qd2, )

#undef PIPE_ISSUE
#undef PIPE_BODY

    __syncthreads();
    if (tid < 96) {
        int rep = blockIdx.x & (NREP - 1);
        atomicAdd(repsum + (size_t)rep * 96 + tid, bins[tid]);
    }
}

// ---------------------------------------------------------------------------
// Final: sum replicas (4-way parallel over reps), node counts from sorted
// boundaries, divide, expand 6 symmetric comps -> 9.
// ---------------------------------------------------------------------------
__global__ __launch_bounds__(384) void final_kernel(
    const float* __restrict__ repsum, const int* __restrict__ gStart,
    float* __restrict__ out, int N)
{
    __shared__ float part[4][96];
    __shared__ float sh[96];
    __shared__ int gs[17];
    int t = threadIdx.x;            // 384 threads
    int r0 = t / 96, gc = t % 96;   // r0 in 0..3
    float s = 0.f;
    #pragma unroll 8
    for (int r = r0; r < NREP; r += 4) s += repsum[(size_t)r * 96 + gc];
    part[r0][gc] = s;
    if (t == 0) {
        gs[16] = N;
        for (int g = 15; g >= 0; --g) {
            unsigned v = (unsigned)gStart[g];
            gs[g] = (v > (unsigned)gs[g + 1]) ? gs[g + 1] : (int)v;  // empty graphs
        }
    }
    __syncthreads();
    if (t < 96) sh[t] = part[0][t] + part[1][t] + part[2][t] + part[3][t];
    __syncthreads();
    if (t < 16) {
        int gN = gs[t + 1] - gs[t];
        float inv = 1.0f / fmaxf((float)gN, 1.0f);
        float m0 = sh[t * 6 + 0] * inv;
        float m1 = sh[t * 6 + 1] * inv;
        float m2 = sh[t * 6 + 2] * inv;
        float m3 = sh[t * 6 + 3] * inv;
        float m4 = sh[t * 6 + 4] * inv;
        float m5 = sh[t * 6 + 5] * inv;
        float* p = out + t * 9;
        p[0] = m0; p[1] = m3; p[2] = m4;
        p[3] = m3; p[4] = m1; p[5] = m5;
        p[6] = m4; p[7] = m5; p[8] = m2;
    }
}

// ---------------------------------------------------------------------------
extern "C" void kernel_launch(void* const* d_in, const int* in_sizes, int n_in,
                              void* d_out, int out_size, void* d_ws, size_t ws_size,
                              hipStream_t stream) {
    const float* dvec   = (const float*)d_in[0];   // [E,3]
    const float* x_edge = (const float*)d_in[1];   // [E,64]
    const int*   eidx   = (const int*)d_in[2];     // [E]
    const int*   batch  = (const int*)d_in[3];     // [N] sorted
    const float* W1     = (const float*)d_in[6];   // [64,64] (in,out)
    const float* b1     = (const float*)d_in[7];   // [64]
    const float* W2     = (const float*)d_in[8];   // [64,1]
    const float* b2     = (const float*)d_in[9];   // [1]

    int E = in_sizes[0] / 3;   // 800000
    int N = in_sizes[3];       // 50000

    // ws: ecnt[N] int | repsum[NREP*96] float | gStart[17] int  (contiguous)
    int*   ecnt   = (int*)d_ws;
    float* repsum = (float*)(ecnt + N);
    int*   gStart = (int*)(repsum + (size_t)NREP * 96);

    hipMemsetAsync(d_ws, 0, ((size_t)N + (size_t)NREP * 96) * 4, stream);
    hipMemsetAsync(gStart, 0xFF, 17 * 4, stream);

    int blocks = (E + 255) / 256;   // covers both E and N in prep
    prep_kernel<<<blocks, 256, 0, stream>>>(eidx, ecnt, E, batch, gStart, N);
    edge_kernel<<<blocks, 256, 0, stream>>>(dvec, x_edge, eidx, batch, ecnt,
                                            W1, b1, W2, b2, repsum, E);
    final_kernel<<<1, 384, 0, stream>>>(repsum, gStart, (float*)d_out, N);
}

// Round 6
// 366.079 us; speedup vs baseline: 1.2129x; 1.0043x over previous
//
#include <hip/hip_runtime.h>

// Problem constants: E=800000 (=3125*256), N=50000, G=16, EMB=64.
#define EMB  64
#define NREP 256   // replica lines for per-graph global atomic spreading

typedef __attribute__((ext_vector_type(8))) short bf16x8;
typedef __attribute__((ext_vector_type(4))) float f32x4;
union BF8 { bf16x8 v; short s[8]; unsigned u[4]; };

// float -> bf16 bits, round-to-nearest-even (finite inputs).
static __device__ __forceinline__ short f2bf(float f) {
    unsigned u = __float_as_uint(f);
    u += 0x7fffu + ((u >> 16) & 1u);
    return (short)(u >> 16);
}

// 2x float -> packed bf16 pair in one instruction (RNE, bit-identical to f2bf).
static __device__ __forceinline__ unsigned cvt2(float lo, float hi) {
    unsigned r;
    asm("v_cvt_pk_bf16_f32 %0, %1, %2" : "=v"(r) : "v"(lo), "v"(hi));
    return r;
}

// ---------------------------------------------------------------------------
// Prep: pure ecnt histogram (gStart replaced by a binary search in
// final_kernel).
// ---------------------------------------------------------------------------
__global__ __launch_bounds__(256) void prep_kernel(
    const int* __restrict__ eidx, int* __restrict__ ecnt, int E)
{
    int t = blockIdx.x * 256 + threadIdx.x;
    if (t < E) atomicAdd(&ecnt[eidx[t]], 1);
}

// ---------------------------------------------------------------------------
// Edge kernel v6 = EXACT R2-passing v3 edge kernel (368us total, edge
// ~110us, absmax 1.22e-4). R4/R5 proved v5's NaN deterministic while its
// source audits semantically identical to this -- so the regression is in
// codegen of one of v5's novelties (packed-f32x2 inner loop and/or
// register-resident b1/W2). BISECT: this round reverts the edge to the
// known-good binary and keeps only the trivially-auditable prep/final
// change. Pass -> bug isolated to v5's edge codegen. Fail -> binary-search
// final (revert fully next).
// ---------------------------------------------------------------------------
__global__ __launch_bounds__(256, 3) void edge_kernel(
    const float* __restrict__ dvec, const float* __restrict__ x_edge,
    const int*   __restrict__ eidx, const int* __restrict__ batch,
    const int*   __restrict__ ecnt,
    const float* __restrict__ W1, const float* __restrict__ b1,
    const float* __restrict__ W2, const float* __restrict__ b2,
    float* __restrict__ repsum, int E)
{
    __shared__ float bins[96];
    __shared__ float sb1N[64], sw2[64], sw2b[64];
    const int tid = threadIdx.x;
    const float NL2E = -1.442695040888963f;  // -log2(e)
    if (tid < 96) bins[tid] = 0.f;
    if (tid < 64) {
        float b = b1[tid], w = W2[tid];
        sb1N[tid] = b * NL2E;   // pre-folded exp2 bias
        sw2[tid]  = w;
        sw2b[tid] = w * b;      // pre-folded w2*z bias
    }
    __syncthreads();

    const int lane = tid & 63, wave = tid >> 6;
    const int col  = lane & 15, quad = lane >> 4;
    const long ebase = (long)blockIdx.x * 256 + wave * 64;

    // --- Prologue 1: scatter-metadata chain issued early (two dependent
    // global loads; latency hides under the constant/Af build below).
    int nn[4] = {0, 0, 0, 0};
    if (quad < 2) {
        #pragma unroll
        for (int nt = 0; nt < 4; ++nt) {
            long e = ebase + nt * 16 + col;
            if (e >= E) e = 0;
            nn[nt] = eidx[e];
        }
    }

    // --- Prologue 2: A fragments (W1 is 16KB, L2-hot).
    // A[m=mt*16+col][k=kt*32+quad*8+j] = W1[k][m]  (bf16 RNE)
    BF8 Af[4][2];
    #pragma unroll
    for (int mt = 0; mt < 4; ++mt)
        #pragma unroll
        for (int kt = 0; kt < 2; ++kt) {
            const float* wp = W1 + (kt * 32 + quad * 8) * 64 + mt * 16 + col;
            #pragma unroll
            for (int j = 0; j < 8; ++j) Af[mt][kt].s[j] = f2bf(wp[j * 64]);
        }

    // --- Prologue 3: resolve metadata (ecnt/batch depend on nn).
    float scl[4] = {0.f, 0.f, 0.f, 0.f};
    int   gg[4]  = {0, 0, 0, 0};
    if (quad < 2) {
        #pragma unroll
        for (int nt = 0; nt < 4; ++nt) {
            long e = ebase + nt * 16 + col;
            float s = __builtin_amdgcn_rcpf((float)max(ecnt[nn[nt]], 1));
            scl[nt] = (e < E) ? s : 0.f;
            gg[nt]  = batch[nn[nt]];
        }
    }

    const float bb2 = b2[0];

// Issue x/dvec loads for sub-tile NT into one stage register set (19 regs).
#define PIPE_ISSUE(NT, XA, XB, XC, XD, DD0, DD1, DD2)                          \
    {                                                                          \
        long e_ = ebase + (NT) * 16 + col;                                     \
        if (e_ >= E) e_ = 0;                                                   \
        const float* xp_ = x_edge + (size_t)e_ * EMB + quad * 8;               \
        XA = *(const f32x4*)(xp_);                                             \
        XB = *(const f32x4*)(xp_ + 4);                                         \
        XC = *(const f32x4*)(xp_ + 32);                                        \
        XD = *(const f32x4*)(xp_ + 36);                                        \
        DD0 = dvec[3 * e_ + 0];                                                \
        DD1 = dvec[3 * e_ + 1];                                                \
        DD2 = dvec[3 * e_ + 2];                                                \
    }

// Consume one stage; PRE (next stage's PIPE_ISSUE) sits after the B
// conversion so its load latency hides under the MFMA+silu block.
#define PIPE_BODY(NT, XA, XB, XC, XD, DD0, DD1, DD2, PRE)                      \
    {                                                                          \
        BF8 B0_, B1_;                                                          \
        B0_.u[0] = cvt2(XA.x, XA.y); B0_.u[1] = cvt2(XA.z, XA.w);              \
        B0_.u[2] = cvt2(XB.x, XB.y); B0_.u[3] = cvt2(XB.z, XB.w);              \
        B1_.u[0] = cvt2(XC.x, XC.y); B1_.u[1] = cvt2(XC.z, XC.w);              \
        B1_.u[2] = cvt2(XD.x, XD.y); B1_.u[3] = cvt2(XD.z, XD.w);              \
        float a_[6] = { DD0*DD0, DD1*DD1, DD2*DD2, DD0*DD1, DD0*DD2, DD1*DD2 };\
        float aN_[6];                                                          \
        _Pragma("unroll")                                                      \
        for (int c = 0; c < 6; ++c) aN_[c] = a_[c] * NL2E;                     \
        PRE                                                                    \
        float acc_[6] = { 0.f, 0.f, 0.f, 0.f, 0.f, 0.f };                      \
        _Pragma("unroll")                                                      \
        for (int mt = 0; mt < 4; ++mt) {                                       \
            f32x4 D_ = { 0.f, 0.f, 0.f, 0.f };                                 \
            D_ = __builtin_amdgcn_mfma_f32_16x16x32_bf16(Af[mt][0].v, B0_.v, D_, 0, 0, 0); \
            D_ = __builtin_amdgcn_mfma_f32_16x16x32_bf16(Af[mt][1].v, B1_.v, D_, 0, 0, 0); \
            _Pragma("unroll")                                                  \
            for (int r = 0; r < 4; ++r) {                                      \
                int   o_  = mt * 16 + quad * 4 + r;                            \
                float y_  = D_[r];                                             \
                float bN_ = sb1N[o_];                                          \
                float wy_ = sw2[o_] * y_;                                      \
                float wb_ = sw2b[o_];                                          \
                _Pragma("unroll")                                              \
                for (int c = 0; c < 6; ++c) {                                  \
                    float arg_ = fmaf(aN_[c], y_, bN_);                        \
                    float ex_  = __builtin_amdgcn_exp2f(arg_);                 \
                    float rr_  = __builtin_amdgcn_rcpf(1.0f + ex_);            \
                    float w2z_ = fmaf(a_[c], wy_, wb_);                        \
                    acc_[c]    = fmaf(w2z_, rr_, acc_[c]);                     \
                }                                                              \
            }                                                                  \
        }                                                                      \
        _Pragma("unroll")                                                      \
        for (int c = 0; c < 6; ++c) {                                          \
            acc_[c] += __shfl_xor(acc_[c], 16, 64);                            \
            acc_[c] += __shfl_xor(acc_[c], 32, 64);                            \
        }                                                                      \
        if (quad < 2) {                                                        \
            _Pragma("unroll")                                                  \
            for (int j = 0; j < 3; ++j) {                                      \
                int c = quad * 3 + j;                                          \
                atomicAdd(&bins[gg[NT] * 6 + c], (acc_[c] + bb2) * scl[NT]);   \
            }                                                                  \
        }                                                                      \
    }

    f32x4 Pxa, Pxb, Pxc, Pxd; float Pd0, Pd1, Pd2;
    f32x4 Qxa, Qxb, Qxc, Qxd; float Qd0, Qd1, Qd2;

    PIPE_ISSUE(0, Pxa, Pxb, Pxc, Pxd, Pd0, Pd1, Pd2)
    PIPE_BODY(0, Pxa, Pxb, Pxc, Pxd, Pd0, Pd1, Pd2,
              PIPE_ISSUE(1, Qxa, Qxb, Qxc, Qxd, Qd0, Qd1, Qd2))
    PIPE_BODY(1, Qxa, Qxb, Qxc, Qxd, Qd0, Qd1, Qd2,
              PIPE_ISSUE(2, Pxa, Pxb, Pxc, Pxd, Pd0, Pd1, Pd2))
    PIPE_BODY(2, Pxa, Pxb, Pxc, Pxd, Pd0, Pd1, Pd2,
              PIPE_ISSUE(3, Qxa, Qxb, Qxc, Qxd, Qd0, Qd1, Qd2))
    PIPE_BODY(3, Qxa, Qxb, Qxc, Qxd, Qd0, Qd1, Qd2, )

#undef PIPE_ISSUE
#undef PIPE_BODY

    __syncthreads();
    if (tid < 96) {
        int rep = blockIdx.x & (NREP - 1);
        atomicAdd(repsum + (size_t)rep * 96 + tid, bins[tid]);
    }
}

// ---------------------------------------------------------------------------
// Final: sum replicas (4-way parallel over reps); graph boundaries via
// binary search on the sorted batch array; divide by node count; expand 6
// symmetric comps -> 9.
// ---------------------------------------------------------------------------
__global__ __launch_bounds__(384) void final_kernel(
    const float* __restrict__ repsum, const int* __restrict__ batch,
    float* __restrict__ out, int N)
{
    __shared__ float part[4][96];
    __shared__ float sh[96];
    __shared__ int gs[17];
    int t = threadIdx.x;            // 384 threads
    int r0 = t / 96, gc = t % 96;   // r0 in 0..3
    if (t < 17) {
        // lower_bound: first i with batch[i] >= t  (batch sorted, 16 graphs)
        int lo = 0, hi = N;
        while (lo < hi) {
            int mid = (lo + hi) >> 1;
            if (batch[mid] < t) lo = mid + 1; else hi = mid;
        }
        gs[t] = lo;
    }
    float s = 0.f;
    #pragma unroll 8
    for (int r = r0; r < NREP; r += 4) s += repsum[(size_t)r * 96 + gc];
    part[r0][gc] = s;
    __syncthreads();
    if (t < 96) sh[t] = part[0][t] + part[1][t] + part[2][t] + part[3][t];
    __syncthreads();
    if (t < 16) {
        int gN = gs[t + 1] - gs[t];
        float inv = 1.0f / fmaxf((float)gN, 1.0f);
        float m0 = sh[t * 6 + 0] * inv;
        float m1 = sh[t * 6 + 1] * inv;
        float m2 = sh[t * 6 + 2] * inv;
        float m3 = sh[t * 6 + 3] * inv;
        float m4 = sh[t * 6 + 4] * inv;
        float m5 = sh[t * 6 + 5] * inv;
        float* p = out + t * 9;
        p[0] = m0; p[1] = m3; p[2] = m4;
        p[3] = m3; p[4] = m1; p[5] = m5;
        p[6] = m4; p[7] = m5; p[8] = m2;
    }
}

// ---------------------------------------------------------------------------
extern "C" void kernel_launch(void* const* d_in, const int* in_sizes, int n_in,
                              void* d_out, int out_size, void* d_ws, size_t ws_size,
                              hipStream_t stream) {
    const float* dvec   = (const float*)d_in[0];   // [E,3]
    const float* x_edge = (const float*)d_in[1];   // [E,64]
    const int*   eidx   = (const int*)d_in[2];     // [E]
    const int*   batch  = (const int*)d_in[3];     // [N] sorted
    const float* W1     = (const float*)d_in[6];   // [64,64] (in,out)
    const float* b1     = (const float*)d_in[7];   // [64]
    const float* W2     = (const float*)d_in[8];   // [64,1]
    const float* b2     = (const float*)d_in[9];   // [1]

    int E = in_sizes[0] / 3;   // 800000
    int N = in_sizes[3];       // 50000

    // ws: ecnt[N] int | repsum[NREP*96] float  (contiguous)
    int*   ecnt   = (int*)d_ws;
    float* repsum = (float*)(ecnt + N);

    hipMemsetAsync(d_ws, 0, ((size_t)N + (size_t)NREP * 96) * 4, stream);

    int blocks = (E + 255) / 256;
    prep_kernel<<<blocks, 256, 0, stream>>>(eidx, ecnt, E);
    edge_kernel<<<blocks, 256, 0, stream>>>(dvec, x_edge, eidx, batch, ecnt,
                                            W1, b1, W2, b2, repsum, E);
    final_kernel<<<1, 384, 0, stream>>>(repsum, batch, (float*)d_out, N);
}